// Round 4
// baseline (112.493 us; speedup 1.0000x reference)
//
#include <hip/hip_runtime.h>
#include <math.h>

typedef float v2f __attribute__((ext_vector_type(2)));

namespace {
__constant__ float kBaseAp[13] = {-31593.7f, 0.106747f, 24606.4f, -78561.9f, 13317.9f,
                                  307387.0f, 84916.1f, -1074690.0f, 2285.04f, 990894.0f,
                                  283920.0f, -161513.0f, -469218.0f};

constexpr double dTO  = 6.08671;
constexpr double dTSN = 1001.38;
constexpr double dTSP = 46.4311;
constexpr double dLAM = 58.0 / 63.0;          // 1 - (1/126 + 1/14)
constexpr double dAO  = 1.0 - 1.0 / dTO;
constexpr double dAN  = 1.0 - 1.0 / dTSN;
constexpr double dAP  = 1.0 - 1.0 / dTSP;

constexpr double cpow(double x, int n) {
    double r = 1.0;
    for (int i = 0; i < n; ++i) r *= x;
    return r;
}
}  // namespace

__device__ __forceinline__ v2f mk2(float a, float b) { v2f r; r.x = a; r.y = b; return r; }

// asinh(z) = log(z + sqrt(z*z + 1)) — used only in the serial fallback
__device__ __forceinline__ float fast_asinh(float z) {
    return __logf(z + sqrtf(__fmaf_rn(z, z, 1.0f)));
}

// ============================================================================
// Wave-parallel scan kernel: one 64-lane wave per batch element, 16 steps/lane.
// Valid for T <= 1024.
//
// Exact linear decomposition:
//   QN=qnB+qnS: QN'=QN-i (prefix sum).  d=(CB-CS)/T_DIFF: d'=lam*d +- i/14,
//   lam=58/63.  qS = Q/10 - 12.6*d.  Vo,Vsn,Vsp: geometric IIRs of pointwise
//   drives -> 5 wave scans + per-lane replay.
//
// n/p electrode symmetry -> packed fp32 (v_pk_fma_f32) via v2f = {n, p}.
// asinh replaced by odd Taylor poly (deg 11), |z|<=0.56 -> rel err ~1.6e-5
// on a ~0.03 V signal (threshold 8.4e-2 absolute).
// Redlich-Kister sum -> E(u) + t*O(u), E/O packed in one Horner chain.
// ============================================================================
__global__ __launch_bounds__(256, 4) void battery_scan_kernel(
    const float* __restrict__ current,     // [B,T]
    const float* __restrict__ init_state,  // [B,8]
    const float* __restrict__ Ap_scale,    // [13]
    const float* __restrict__ An0_scale,   // [1]
    float* __restrict__ out,               // [B,T]
    int B, int T)
{
    constexpr int L = 16;                       // timesteps per lane
    const int lane = threadIdx.x & 63;
    const int wid  = threadIdx.x >> 6;
    const int b    = blockIdx.x * (blockDim.x >> 6) + wid;
    if (b >= B) return;                         // wave-uniform

    // ---- scalar constants ----
    const float invF   = (float)(1.0 / 96487.0);
    const float invQS  = (float)(1.0 / (7600.0 / 0.6 * 0.1));  // 1/1266.667
    const float inv14  = (float)(1.0 / 14.0);
    const float lam    = (float)dLAM,  lam16 = (float)cpow(dLAM, L);
    const float ao     = (float)dAO,   ao16  = (float)cpow(dAO, L);
    const float an     = (float)dAN,   an16  = (float)cpow(dAN, L);
    const float ap     = (float)dAP,   ap16  = (float)cpow(dAP, L);
    const float c1n = (float)(1.0 / (0.000437545 * 2.0 * 2120.96));   // z = i*c1*rsqrt(x(1-x))
    const float c1p = (float)(1.0 / (0.00030962 * 2.0 * 248898.0));
    const float cA  = 0.1f * invQS;
    const float cB  = 12.6f * invQS;
    const float cRO = 0.117215f * (float)(1.0 / dTO);
    const float CC  = 4.03f - 0.01f;            // U0P - U0N

    // ---- packed constants ----
    const v2f c1v   = mk2(c1n, c1p);
    const v2f c14v  = mk2(inv14, -inv14);       // d-drive signs: dn +i/14, dp -i/14
    const v2f cAsv  = mk2(-cA, cA);             // x drift from Q-mode: xn -, xp +
    const v2f lm1v  = mk2(lam - 1.0f, lam - 1.0f);
    const v2f mcBv  = mk2(-cB, -cB);
    const v2f avnp  = mk2(an, ap);              // IIR poles {n, p}
    const v2f ph1A  = mk2(1.0f, lam);           // phase-1 packed accum poles
    const v2f ph1B  = mk2(1.0f, inv14);
    // asinh(z)/z = P(z^2), Taylor deg 5 in z^2 (|z| <= 0.56 -> rel err ~1.6e-5)
    const v2f az1 = mk2(-1.0f/6.0f, -1.0f/6.0f);
    const v2f az2 = mk2(3.0f/40.0f, 3.0f/40.0f);
    const v2f az3 = mk2(-15.0f/336.0f, -15.0f/336.0f);
    const v2f az4 = mk2(105.0f/3456.0f, 105.0f/3456.0f);
    const v2f az5 = mk2(-945.0f/42240.0f, -945.0f/42240.0f);

    // ---- per-element init state ----
    const float* st = init_state + (size_t)b * 8;
    const float Tb = st[0], Vo0 = st[1], Vsn0 = st[2], Vsp0 = st[3];
    const float qnB0 = st[4], qnS0 = st[5], qpB0 = st[6], qpS0 = st[7];
    const float QN0 = qnB0 + qnS0;
    const float QP0 = qpB0 + qpS0;
    const float dn0 = qnB0 * (float)(1.0/126.0) - qnS0 * inv14;
    const float dp0 = qpB0 * (float)(1.0/126.0) - qpS0 * inv14;
    const float coefVs = 8.3144621f * Tb * invF * 2.0f;   // RGAS*Tb/(F*ALPHA)
    const float coefL  = 8.3144621f * Tb * invF;
    const v2f cVv = mk2(coefVs * (float)(1.0 / dTSN),     // pre-scaled by 1/TS*
                        coefVs * (float)(1.0 / dTSP));

    // ---- RK even/odd Horner coefficients, pre-scaled by 1/F; packed {E,O} ----
    float alpha[13], beta[13];
    #pragma unroll
    for (int k = 0; k < 13; ++k) {
        const float A = Ap_scale[k] * kBaseAp[k] * invF;
        alpha[k] = A * (1.0f + 0.5f * (float)k);
        beta[k]  = -A * (0.5f * (float)k);
    }
    const v2f eo0 = mk2(beta[1],              (Ap_scale[0] * kBaseAp[0] * invF) + beta[2]);
    const v2f eo1 = mk2(alpha[1] + beta[3],   alpha[2]  + beta[4]);
    const v2f eo2 = mk2(alpha[3] + beta[5],   alpha[4]  + beta[6]);
    const v2f eo3 = mk2(alpha[5] + beta[7],   alpha[6]  + beta[8]);
    const v2f eo4 = mk2(alpha[7] + beta[9],   alpha[8]  + beta[10]);
    const v2f eo5 = mk2(alpha[9] + beta[11],  alpha[10] + beta[12]);
    const v2f eo6 = mk2(alpha[11],            alpha[12]);
    const float AnF = An0_scale[0] * 86.19f * invF;

    // ---- load this lane's 16 currents (float4, tail-guarded) ----
    const float* row = current + (size_t)b * T;
    const int t0 = lane * L;
    float cur[L];
    #pragma unroll
    for (int k = 0; k < L / 4; ++k) {
        const int t = t0 + 4 * k;
        if (t + 4 <= T) {
            const float4 v = *reinterpret_cast<const float4*>(row + t);
            cur[4*k+0] = v.x; cur[4*k+1] = v.y; cur[4*k+2] = v.z; cur[4*k+3] = v.w;
        } else {
            #pragma unroll
            for (int m = 0; m < 4; ++m)
                cur[4*k+m] = (t + m < T) ? row[t + m] : 0.0f;
        }
    }

    // ---- phase 1: packed local reduction {s_loc, cH} ----
    v2f acc1 = mk2(0.0f, 0.0f);
    #pragma unroll
    for (int j = 0; j < L; ++j)
        acc1 = ph1A * acc1 + cur[j] * ph1B;     // {s += i, cH = lam*cH + i/14}
    float s_loc = acc1.x, cH = acc1.y;

    // ---- phase 2: wave scans (cumsum + one affine) ----
    float s = s_loc;
    #pragma unroll
    for (int d = 1; d < 64; d <<= 1) {
        const float o = __shfl_up(s, (unsigned)d, 64);
        if (lane >= d) s += o;
    }
    const float Sx = s - s_loc;          // exclusive prefix sum at segment start

    float Ah = lam16, Ch = cH;           // affine composition (A, C): y -> A*y + C
    #pragma unroll
    for (int d = 1; d < 64; d <<= 1) {
        const float A2 = __shfl_up(Ah, (unsigned)d, 64);
        const float C2 = __shfl_up(Ch, (unsigned)d, 64);
        if (lane >= d) { Ch = __fmaf_rn(Ah, C2, Ch); Ah *= A2; }
    }
    float Ax = __shfl_up(Ah, 1u, 64);
    float Cx = __shfl_up(Ch, 1u, 64);
    if (lane == 0) { Ax = 1.0f; Cx = 0.0f; }
    const float h    = Cx;               // zero-init driven d-solution at t0
    const float lamt = Ax;               // lam^t0

    // ---- segment-start state (then advanced incrementally, exact algebra) ----
    v2f dv = mk2(lamt, lamt) * mk2(dn0, dp0) + mk2(h, -h);
    v2f qv = mk2(QN0 - Sx, QP0 + Sx);
    v2f xv = qv * cA + mcBv * dv;

    // ---- phase 3: replay; packed n/p math ----
    float c_o = 0.0f;
    v2f  c_sv = mk2(0.0f, 0.0f);
    v2f  nsv[L];
    float epn[L];

    #pragma unroll
    for (int j = 0; j < L; ++j) {
        const float i = cur[j];

        // surface overpotential drive from state at t  (v = cV * asinh(z))
        const v2f p = xv - xv * xv;                         // x*(1-x)
        v2f r; r.x = __frsqrt_rn(p.x); r.y = __frsqrt_rn(p.y);
        const v2f z  = (i * c1v) * r;
        const v2f z2 = z * z;
        v2f P = az5;
        P = P * z2 + az4;
        P = P * z2 + az3;
        P = P * z2 + az2;
        P = P * z2 + az1;
        const v2f zP = z * P;
        const v2f v  = cVv * (z + z * (z2 * (P - P + 1.0f) - z2) + (zP - zP)) // placeholder avoided
                       ;
        // NOTE: line above must be exactly cV * z * (1 + z2*P'); simpler direct form:
        const v2f vdrive = cVv * (z + z * z2 * P);          // cV * z * (1 + z2*P)
        nsv[j] = vdrive;
        c_sv = avnp * c_sv + vdrive;
        c_o  = __fmaf_rn(ao, c_o, i * cRO);

        // advance linear states to t+1 (exact): d' = lam*d +- i/14; x' = x - cB*dd -+ cA*i
        const v2f dd = lm1v * dv + i * c14v;                // (lam-1)*d + drive
        dv = dv + dd;
        xv = xv + mcBv * dd + i * cAsv;

        // electrode potentials from state at t+1
        const v2f w = 1.0f - xv;
        const float lr = __logf(__fdividef(xv.x * w.y, xv.y * w.x));

        const v2f tv = 2.0f * xv - 1.0f;                    // {tn, tp}
        const float u = tv.y * tv.y;
        v2f EO = eo6;
        EO = EO * u + eo5;
        EO = EO * u + eo4;
        EO = EO * u + eo3;
        EO = EO * u + eo2;
        EO = EO * u + eo1;
        EO = EO * u + eo0;
        const float rk = __fmaf_rn(tv.y, EO.y, EO.x);       // (RK sum)/F

        epn[j] = CC + __fmaf_rn(coefL, lr, __fmaf_rn(-AnF, tv.x, rk));
    }

    // ---- phase 4: wave scans for the three V IIRs ({n,p} packed + o scalar) ----
    float Ao = ao16, Co = c_o;
    v2f Anp = mk2(an16, ap16), Cnp = c_sv;
    #pragma unroll
    for (int d = 1; d < 64; d <<= 1) {
        const float Ao2 = __shfl_up(Ao, (unsigned)d, 64);
        const float Co2 = __shfl_up(Co, (unsigned)d, 64);
        v2f A2, C2;
        A2.x = __shfl_up(Anp.x, (unsigned)d, 64);
        A2.y = __shfl_up(Anp.y, (unsigned)d, 64);
        C2.x = __shfl_up(Cnp.x, (unsigned)d, 64);
        C2.y = __shfl_up(Cnp.y, (unsigned)d, 64);
        if (lane >= d) {
            Co = __fmaf_rn(Ao, Co2, Co);  Ao *= Ao2;
            Cnp = Anp * C2 + Cnp;         Anp = Anp * A2;
        }
    }
    float Axo = __shfl_up(Ao, 1u, 64), Cxo = __shfl_up(Co, 1u, 64);
    v2f Axnp, Cxnp;
    Axnp.x = __shfl_up(Anp.x, 1u, 64);  Axnp.y = __shfl_up(Anp.y, 1u, 64);
    Cxnp.x = __shfl_up(Cnp.x, 1u, 64);  Cxnp.y = __shfl_up(Cnp.y, 1u, 64);
    if (lane == 0) {
        Axo = 1.0f; Cxo = 0.0f;
        Axnp = mk2(1.0f, 1.0f); Cxnp = mk2(0.0f, 0.0f);
    }
    float vo = __fmaf_rn(Axo, Vo0, Cxo);          // V values at segment start
    v2f  vsv = Axnp * mk2(Vsn0, Vsp0) + Cxnp;

    // ---- phase 5: replay IIRs, form outputs ----
    #pragma unroll
    for (int j = 0; j < L; ++j) {
        vo  = __fmaf_rn(ao, vo, cur[j] * cRO);
        vsv = avnp * vsv + nsv[j];
        epn[j] -= vo + vsv.x + vsv.y;             // V_t
    }

    // ---- stores (float4, tail-guarded) ----
    float* orow = out + (size_t)b * T;
    #pragma unroll
    for (int k = 0; k < L / 4; ++k) {
        const int t = t0 + 4 * k;
        if (t + 4 <= T) {
            *reinterpret_cast<float4*>(orow + t) =
                make_float4(epn[4*k+0], epn[4*k+1], epn[4*k+2], epn[4*k+3]);
        } else {
            #pragma unroll
            for (int m = 0; m < 4; ++m)
                if (t + m < T) orow[t + m] = epn[4*k+m];
        }
    }
}

// ============================================================================
// Serial fallback for T > 1024 — correctness insurance only.
// ============================================================================
__global__ __launch_bounds__(64) void battery_serial_kernel(
    const float* __restrict__ current, const float* __restrict__ init_state,
    const float* __restrict__ Ap_scale, const float* __restrict__ An0_scale,
    float* __restrict__ out, int B, int T)
{
    const int b = blockIdx.x * blockDim.x + threadIdx.x;
    if (b >= B) return;

    const float invF = (float)(1.0 / 96487.0);
    const float RO = 0.117215f, KN = 2120.96f, KP = 248898.0f;
    const float invQS = (float)(1.0 / (7600.0 / 0.6 * 0.1));
    const float iVB = (float)(1.0 / 126.0), iVS = (float)(1.0 / 14.0);
    const float invSN = (float)(1.0 / 0.000437545), invSP = (float)(1.0 / 0.00030962);
    const float invTO = (float)(1.0 / dTO), invTSN = (float)(1.0 / dTSN), invTSP = (float)(1.0 / dTSP);
    const float U0P = 4.03f, U0N = 0.01f;

    float Ap[13], Apk[13];
    #pragma unroll
    for (int k = 0; k < 13; ++k) { Ap[k] = Ap_scale[k] * kBaseAp[k]; Apk[k] = Ap[k] * (float)k; }
    const float An0 = An0_scale[0] * 86.19f;

    const float* st = init_state + (size_t)b * 8;
    float Tb = st[0], Vo = st[1], Vsn = st[2], Vsp = st[3];
    float qnB = st[4], qnS = st[5], qpB = st[6], qpS = st[7];
    const float coefVs = 8.3144621f * Tb * invF * 2.0f;
    const float coefL  = 8.3144621f * Tb * invF;

    const float* cur = current + (size_t)b * T;
    float* op = out + (size_t)b * T;

    for (int t = 0; t < T; ++t) {
        const float i = cur[t];
        float xnS = qnS * invQS, xpS = qpS * invQS;
        float Jn0 = KN * sqrtf(xnS * (1.0f - xnS));
        float Jp0 = KP * sqrtf(xpS * (1.0f - xpS));
        float dBSn = qnB * iVB - qnS * iVS;
        float dBSp = qpB * iVB - qpS * iVS;
        float zn = __fdividef(i * invSN, 2.0f * Jn0);
        float zp = __fdividef(i * invSP, 2.0f * Jp0);
        Vo  += (i * RO - Vo) * invTO;
        Vsn += (coefVs * fast_asinh(zn) - Vsn) * invTSN;
        Vsp += (coefVs * fast_asinh(zp) - Vsp) * invTSP;
        qnB -= dBSn; qnS += dBSn - i; qpB -= dBSp; qpS += i + dBSp;

        float xp = qpS * invQS, xn = qnS * invQS;
        float lp = __logf(__fdividef(1.0f - xp, xp));
        float ln = __logf(__fdividef(1.0f - xn, xn));
        float tp = 2.0f * xp - 1.0f, cp2 = 2.0f * xp * (1.0f - xp);
        float sum = Ap[0] * tp, pkm1 = 1.0f, pk = tp;
        #pragma unroll
        for (int k = 1; k < 13; ++k) {
            float pk1 = pk * tp;
            sum = __fmaf_rn(Ap[k], pk1, sum);
            sum = __fmaf_rn(-Apk[k] * cp2, pkm1, sum);
            pkm1 = pk; pk = pk1;
        }
        float tn = 2.0f * xn - 1.0f;
        op[t] = (U0P - U0N) + coefL * (lp - ln) + (sum - An0 * tn) * invF - Vo - Vsn - Vsp;
    }
}

extern "C" void kernel_launch(void* const* d_in, const int* in_sizes, int n_in,
                              void* d_out, int out_size, void* d_ws, size_t ws_size,
                              hipStream_t stream) {
    const float* current    = (const float*)d_in[0];
    const float* init_state = (const float*)d_in[1];
    const float* Ap_scale   = (const float*)d_in[2];
    const float* An0_scale  = (const float*)d_in[3];
    float* out = (float*)d_out;

    const int B = in_sizes[1] / 8;   // init_state is [B,8]
    const int T = in_sizes[0] / B;   // current is [B,T]

    if (T <= 1024) {
        // one 64-lane wave per batch element, 4 waves per 256-thread block
        dim3 block(256);
        dim3 grid((B + 3) / 4);
        hipLaunchKernelGGL(battery_scan_kernel, grid, block, 0, stream,
                           current, init_state, Ap_scale, An0_scale, out, B, T);
    } else {
        dim3 block(64);
        dim3 grid((B + 63) / 64);
        hipLaunchKernelGGL(battery_serial_kernel, grid, block, 0, stream,
                           current, init_state, Ap_scale, An0_scale, out, B, T);
    }
}

// Round 6
// 95.425 us; speedup vs baseline: 1.1789x; 1.1789x over previous
//
#include <hip/hip_runtime.h>
#include <math.h>

namespace {
__constant__ float kBaseAp[13] = {-31593.7f, 0.106747f, 24606.4f, -78561.9f, 13317.9f,
                                  307387.0f, 84916.1f, -1074690.0f, 2285.04f, 990894.0f,
                                  283920.0f, -161513.0f, -469218.0f};

constexpr double dTO  = 6.08671;
constexpr double dTSN = 1001.38;
constexpr double dTSP = 46.4311;
constexpr double dLAM = 58.0 / 63.0;          // 1 - (1/126 + 1/14)
constexpr double dAO  = 1.0 - 1.0 / dTO;
constexpr double dAN  = 1.0 - 1.0 / dTSN;
constexpr double dAP  = 1.0 - 1.0 / dTSP;

constexpr double cpow(double x, int n) {
    double r = 1.0;
    for (int i = 0; i < n; ++i) r *= x;
    return r;
}
}  // namespace

// asinh(z) = log(z + sqrt(z*z + 1)) — serial fallback only
__device__ __forceinline__ float fast_asinh(float z) {
    return __logf(z + sqrtf(__fmaf_rn(z, z, 1.0f)));
}

// ============================================================================
// Wave-parallel scan kernel: one 64-lane wave per batch element, 16 steps/lane.
// Valid for T <= 1024.
//
// Exact linear decomposition (R2/R3, verified passing):
//   QN=qnB+qnS: QN'=QN-i (prefix sum).  d: d'=lam*d +- i/14, lam=58/63.
//   x = q/Q_S_MAX = (Q -+ S)*cA - cB*d.  Vo,Vsn,Vsp: geometric IIRs.
//
// R5: per-segment linearization. x drifts <= ~6e-3 over a 16-step segment:
//   * potentials: epn_j = K0 + Kn*dxn + Kp*dxp (U and grad at segment anchor;
//     2nd-order error <= ~2e-4 V vs 8.4e-2 threshold)
//   * drives: g = c1*rsqrt(x(1-x)) frozen at anchor; vn = cVn*asinh(i*g) via
//     deg-7 odd Taylor (err ~8e-6 V); vp = cVp*c1p*rp*i exactly (z_p<=0.007).
//   -> hot loop: ~23 VALU, 0 transcendentals per step.
// Scans: affine A lane-uniform per level (pole^16) -> C-only scans with
// compile-time pole^(16*2^k) tables; per-lane anchors pole^(16*lane) via
// binary exponentiation over lane bits (no exp2/log2 — glibc macro hazard).
// ============================================================================
__global__ __launch_bounds__(256, 4) void battery_scan_kernel(
    const float* __restrict__ current,     // [B,T]
    const float* __restrict__ init_state,  // [B,8]
    const float* __restrict__ Ap_scale,    // [13]
    const float* __restrict__ An0_scale,   // [1]
    float* __restrict__ out,               // [B,T]
    int B, int T)
{
    constexpr int L = 16;                       // timesteps per lane
    const int lane = threadIdx.x & 63;
    const int wid  = threadIdx.x >> 6;
    const int b    = blockIdx.x * (blockDim.x >> 6) + wid;
    if (b >= B) return;                         // wave-uniform

    // ---- constants ----
    const float invF   = (float)(1.0 / 96487.0);
    const float invQS  = (float)(1.0 / (7600.0 / 0.6 * 0.1));
    const float inv14  = (float)(1.0 / 14.0);
    const float lam    = (float)dLAM;
    const float lm1    = (float)(dLAM - 1.0);
    const float ao     = (float)dAO, an = (float)dAN, ap = (float)dAP;
    const float c1n = (float)(1.0 / (0.000437545 * 2.0 * 2120.96));
    const float c1p = (float)(1.0 / (0.00030962 * 2.0 * 248898.0));
    const float cA  = 0.1f * invQS;
    const float cB  = 12.6f * invQS;
    const float cRO    = (float)(0.117215 / dTO);
    const float invcRO = (float)(dTO / 0.117215);
    const float CC  = 4.03f - 0.01f;            // U0P - U0N
    // asinh(z)/z = 1 + z2*(a1 + z2*(a2 + z2*a3)), |z|<=0.56
    const float a1 = -1.0f / 6.0f, a2 = 3.0f / 40.0f, a3 = -15.0f / 336.0f;

    // scan level constants pole^(16*2^k), k=0..5 (compile-time)
    const float lamL[6] = {(float)cpow(dLAM,16),(float)cpow(dLAM,32),(float)cpow(dLAM,64),
                           (float)cpow(dLAM,128),(float)cpow(dLAM,256),(float)cpow(dLAM,512)};
    const float aoL[6]  = {(float)cpow(dAO,16),(float)cpow(dAO,32),(float)cpow(dAO,64),
                           (float)cpow(dAO,128),(float)cpow(dAO,256),(float)cpow(dAO,512)};
    const float anL[6]  = {(float)cpow(dAN,16),(float)cpow(dAN,32),(float)cpow(dAN,64),
                           (float)cpow(dAN,128),(float)cpow(dAN,256),(float)cpow(dAN,512)};
    const float apL[6]  = {(float)cpow(dAP,16),(float)cpow(dAP,32),(float)cpow(dAP,64),
                           (float)cpow(dAP,128),(float)cpow(dAP,256),(float)cpow(dAP,512)};

    // per-lane anchors pole^(16*lane): binary exponentiation over lane bits
    float lamt = 1.0f, aot = 1.0f, ant = 1.0f, apt = 1.0f;
    #pragma unroll
    for (int k = 0; k < 6; ++k) {
        if (lane & (1 << k)) {
            lamt *= lamL[k];
            aot  *= aoL[k];
            ant  *= anL[k];
            apt  *= apL[k];
        }
    }

    // ---- per-element init state ----
    const float* st = init_state + (size_t)b * 8;
    const float Tb = st[0], Vo0 = st[1], Vsn0 = st[2], Vsp0 = st[3];
    const float qnB0 = st[4], qnS0 = st[5], qpB0 = st[6], qpS0 = st[7];
    const float QN0 = qnB0 + qnS0;
    const float QP0 = qpB0 + qpS0;
    const float dn0 = qnB0 * (float)(1.0/126.0) - qnS0 * inv14;
    const float dp0 = qpB0 * (float)(1.0/126.0) - qpS0 * inv14;
    const float coefVs = 8.3144621f * Tb * invF * 2.0f;
    const float coefL  = 8.3144621f * Tb * invF;
    const float cVn = coefVs * (float)(1.0 / dTSN);
    const float cVp = coefVs * (float)(1.0 / dTSP);

    // ---- RK E/O Horner coefficients (invF folded) + derivative coeffs ----
    float alpha[13], beta[13];
    #pragma unroll
    for (int k = 0; k < 13; ++k) {
        const float A = Ap_scale[k] * kBaseAp[k] * invF;
        alpha[k] = A * (1.0f + 0.5f * (float)k);
        beta[k]  = -A * (0.5f * (float)k);
    }
    const float e0 = beta[1];
    const float e1 = alpha[1] + beta[3];
    const float e2 = alpha[3] + beta[5];
    const float e3 = alpha[5] + beta[7];
    const float e4 = alpha[7] + beta[9];
    const float e5 = alpha[9] + beta[11];
    const float e6 = alpha[11];
    const float o0 = (Ap_scale[0] * kBaseAp[0] * invF) + beta[2];
    const float o1 = alpha[2]  + beta[4];
    const float o2 = alpha[4]  + beta[6];
    const float o3 = alpha[6]  + beta[8];
    const float o4 = alpha[8]  + beta[10];
    const float o5 = alpha[10] + beta[12];
    const float o6 = alpha[12];
    // E'(u), O'(u) coefficients
    const float ed1 = e1, ed2 = 2.0f*e2, ed3 = 3.0f*e3, ed4 = 4.0f*e4, ed5 = 5.0f*e5, ed6 = 6.0f*e6;
    const float od1 = o1, od2 = 2.0f*o2, od3 = 3.0f*o3, od4 = 4.0f*o4, od5 = 5.0f*o5, od6 = 6.0f*o6;
    const float AnF = An0_scale[0] * 86.19f * invF;

    // ---- load this lane's 16 currents (float4, tail-guarded) ----
    const float* row = current + (size_t)b * T;
    const int t0 = lane * L;
    float cur[L];
    #pragma unroll
    for (int k = 0; k < L / 4; ++k) {
        const int t = t0 + 4 * k;
        if (t + 4 <= T) {
            const float4 v = *reinterpret_cast<const float4*>(row + t);
            cur[4*k+0] = v.x; cur[4*k+1] = v.y; cur[4*k+2] = v.z; cur[4*k+3] = v.w;
        } else {
            #pragma unroll
            for (int m = 0; m < 4; ++m)
                cur[4*k+m] = (t + m < T) ? row[t + m] : 0.0f;
        }
    }

    // ---- phase 1: local reductions for S (cumsum) and h (d' = lam*d + i/14) ----
    float s_loc = 0.0f, cH = 0.0f;
    #pragma unroll
    for (int j = 0; j < L; ++j) {
        s_loc += cur[j];
        cH = __fmaf_rn(lam, cH, cur[j] * inv14);
    }

    // ---- phase 2: cumsum scan + C-only affine scan for h ----
    float s = s_loc;
    #pragma unroll
    for (int d = 1; d < 64; d <<= 1) {
        const float o = __shfl_up(s, (unsigned)d, 64);
        if (lane >= d) s += o;
    }
    const float Sx = s - s_loc;          // exclusive prefix sum at segment start

    float Ch = cH;
    #pragma unroll
    for (int k = 0; k < 6; ++k) {
        const int d = 1 << k;
        const float o = __shfl_up(Ch, (unsigned)d, 64);
        if (lane >= d) Ch = __fmaf_rn(lamL[k], o, Ch);
    }
    float h = __shfl_up(Ch, 1u, 64);
    if (lane == 0) h = 0.0f;

    // ---- anchor state at t0 ----
    float dn = __fmaf_rn(lamt, dn0, h);
    float dp = __fmaf_rn(lamt, dp0, -h);
    const float xn0 = (QN0 - Sx) * cA - dn * cB;
    const float xp0 = (QP0 + Sx) * cA - dp * cB;

    // ---- per-segment heavy eval (once per wave) ----
    const float pn0 = __fmaf_rn(-xn0, xn0, xn0);          // xn0*(1-xn0)
    const float pp0 = __fmaf_rn(-xp0, xp0, xp0);
    const float rn = __frsqrt_rn(pn0), rp = __frsqrt_rn(pp0);
    const float rn2 = rn * rn, rp2 = rp * rp;             // 1/(x(1-x))
    const float gn  = c1n * rn;
    const float gn2 = gn * gn;
    const float kn  = cVn * gn;
    const float kp  = (cVp * c1p) * rp;
    const float fxn = __logf(__fdividef(1.0f - xn0, xn0));
    const float fxp = __logf(__fdividef(1.0f - xp0, xp0));
    const float tp0 = 2.0f * xp0 - 1.0f;
    const float u0  = tp0 * tp0;
    float E = __fmaf_rn(e6, u0, e5);
    E = __fmaf_rn(E, u0, e4); E = __fmaf_rn(E, u0, e3);
    E = __fmaf_rn(E, u0, e2); E = __fmaf_rn(E, u0, e1); E = __fmaf_rn(E, u0, e0);
    float O = __fmaf_rn(o6, u0, o5);
    O = __fmaf_rn(O, u0, o4); O = __fmaf_rn(O, u0, o3);
    O = __fmaf_rn(O, u0, o2); O = __fmaf_rn(O, u0, o1); O = __fmaf_rn(O, u0, o0);
    float Ep = __fmaf_rn(ed6, u0, ed5);
    Ep = __fmaf_rn(Ep, u0, ed4); Ep = __fmaf_rn(Ep, u0, ed3);
    Ep = __fmaf_rn(Ep, u0, ed2); Ep = __fmaf_rn(Ep, u0, ed1);
    float Op = __fmaf_rn(od6, u0, od5);
    Op = __fmaf_rn(Op, u0, od4); Op = __fmaf_rn(Op, u0, od3);
    Op = __fmaf_rn(Op, u0, od2); Op = __fmaf_rn(Op, u0, od1);
    const float rkf0 = __fmaf_rn(tp0, O, E);              // RK/F at anchor
    float Fp = __fmaf_rn(2.0f * tp0, Ep, O);              // dRK/dt = 2t E' + O + 2u O'
    Fp = __fmaf_rn(2.0f * u0, Op, Fp);
    const float tn0 = 2.0f * xn0 - 1.0f;
    const float K0 = CC + coefL * (fxp - fxn) + rkf0 - AnF * tn0;
    const float Kn = __fmaf_rn(coefL, rn2, -2.0f * AnF);  // -dVen/dxn
    const float Kp = __fmaf_rn(-coefL, rp2, 2.0f * Fp);   // dVep/dxp

    // ---- phase 3: hot loop — ~23 VALU, 0 transcendentals per step ----
    float c_o = 0.0f, c_sn = 0.0f, c_sp = 0.0f;
    float dxn = 0.0f, dxp = 0.0f;
    float nsn[L], nsp[L], epn[L];
    #pragma unroll
    for (int j = 0; j < L; ++j) {
        const float i = cur[j];
        // drives from state at t (frozen g)
        const float i2 = i * i;
        const float z2 = i2 * gn2;
        float Q = __fmaf_rn(a3, z2, a2);
        Q = __fmaf_rn(Q, z2, a1);
        const float w  = __fmaf_rn(z2, Q, 1.0f);
        const float vn = (i * kn) * w;
        const float vp = i * kp;
        nsn[j] = vn; nsp[j] = vp;
        c_sn = __fmaf_rn(an, c_sn, vn);
        c_sp = __fmaf_rn(ap, c_sp, vp);
        c_o  = __fmaf_rn(ao, c_o, i);
        // linear state advance to t+1
        const float t14 = i * inv14;
        const float ddn = __fmaf_rn(lm1, dn, t14);
        const float ddp = __fmaf_rn(lm1, dp, -t14);
        dn += ddn; dp += ddp;
        dxn = __fmaf_rn(-cB, ddn, dxn); dxn = __fmaf_rn(-cA, i, dxn);
        dxp = __fmaf_rn(-cB, ddp, dxp); dxp = __fmaf_rn( cA, i, dxp);
        // linearized potentials at t+1
        epn[j] = __fmaf_rn(Kn, dxn, __fmaf_rn(Kp, dxp, K0));
    }

    // ---- phase 4: three C-only IIR scans ----
    float Co = c_o, Cn = c_sn, Cp = c_sp;
    #pragma unroll
    for (int k = 0; k < 6; ++k) {
        const int d = 1 << k;
        const float oo = __shfl_up(Co, (unsigned)d, 64);
        const float on = __shfl_up(Cn, (unsigned)d, 64);
        const float op = __shfl_up(Cp, (unsigned)d, 64);
        if (lane >= d) {
            Co = __fmaf_rn(aoL[k], oo, Co);
            Cn = __fmaf_rn(anL[k], on, Cn);
            Cp = __fmaf_rn(apL[k], op, Cp);
        }
    }
    float Cxo = __shfl_up(Co, 1u, 64);
    float Cxn = __shfl_up(Cn, 1u, 64);
    float Cxp = __shfl_up(Cp, 1u, 64);
    if (lane == 0) { Cxo = 0.0f; Cxn = 0.0f; Cxp = 0.0f; }
    float vo  = __fmaf_rn(aot, Vo0 * invcRO, Cxo);   // Vo/cRO at segment start
    float vsn = __fmaf_rn(ant, Vsn0, Cxn);
    float vsp = __fmaf_rn(apt, Vsp0, Cxp);

    // ---- phase 5: replay IIRs, form outputs ----
    #pragma unroll
    for (int j = 0; j < L; ++j) {
        vo  = __fmaf_rn(ao, vo, cur[j]);
        vsn = __fmaf_rn(an, vsn, nsn[j]);
        vsp = __fmaf_rn(ap, vsp, nsp[j]);
        epn[j] = (epn[j] - vsn - vsp) - cRO * vo;   // V_t
    }

    // ---- stores (float4, tail-guarded) ----
    float* orow = out + (size_t)b * T;
    #pragma unroll
    for (int k = 0; k < L / 4; ++k) {
        const int t = t0 + 4 * k;
        if (t + 4 <= T) {
            *reinterpret_cast<float4*>(orow + t) =
                make_float4(epn[4*k+0], epn[4*k+1], epn[4*k+2], epn[4*k+3]);
        } else {
            #pragma unroll
            for (int m = 0; m < 4; ++m)
                if (t + m < T) orow[t + m] = epn[4*k+m];
        }
    }
}

// ============================================================================
// Serial fallback for T > 1024 — correctness insurance only.
// ============================================================================
__global__ __launch_bounds__(64) void battery_serial_kernel(
    const float* __restrict__ current, const float* __restrict__ init_state,
    const float* __restrict__ Ap_scale, const float* __restrict__ An0_scale,
    float* __restrict__ out, int B, int T)
{
    const int b = blockIdx.x * blockDim.x + threadIdx.x;
    if (b >= B) return;

    const float invF = (float)(1.0 / 96487.0);
    const float RO = 0.117215f, KN = 2120.96f, KP = 248898.0f;
    const float invQS = (float)(1.0 / (7600.0 / 0.6 * 0.1));
    const float iVB = (float)(1.0 / 126.0), iVS = (float)(1.0 / 14.0);
    const float invSN = (float)(1.0 / 0.000437545), invSP = (float)(1.0 / 0.00030962);
    const float invTO = (float)(1.0 / dTO), invTSN = (float)(1.0 / dTSN), invTSP = (float)(1.0 / dTSP);
    const float U0P = 4.03f, U0N = 0.01f;

    float Ap[13], Apk[13];
    #pragma unroll
    for (int k = 0; k < 13; ++k) { Ap[k] = Ap_scale[k] * kBaseAp[k]; Apk[k] = Ap[k] * (float)k; }
    const float An0 = An0_scale[0] * 86.19f;

    const float* st = init_state + (size_t)b * 8;
    float Tb = st[0], Vo = st[1], Vsn = st[2], Vsp = st[3];
    float qnB = st[4], qnS = st[5], qpB = st[6], qpS = st[7];
    const float coefVs = 8.3144621f * Tb * invF * 2.0f;
    const float coefL  = 8.3144621f * Tb * invF;

    const float* cur = current + (size_t)b * T;
    float* op = out + (size_t)b * T;

    for (int t = 0; t < T; ++t) {
        const float i = cur[t];
        float xnS = qnS * invQS, xpS = qpS * invQS;
        float Jn0 = KN * sqrtf(xnS * (1.0f - xnS));
        float Jp0 = KP * sqrtf(xpS * (1.0f - xpS));
        float dBSn = qnB * iVB - qnS * iVS;
        float dBSp = qpB * iVB - qpS * iVS;
        float zn = __fdividef(i * invSN, 2.0f * Jn0);
        float zp = __fdividef(i * invSP, 2.0f * Jp0);
        Vo  += (i * RO - Vo) * invTO;
        Vsn += (coefVs * fast_asinh(zn) - Vsn) * invTSN;
        Vsp += (coefVs * fast_asinh(zp) - Vsp) * invTSP;
        qnB -= dBSn; qnS += dBSn - i; qpB -= dBSp; qpS += i + dBSp;

        float xp = qpS * invQS, xn = qnS * invQS;
        float lp = __logf(__fdividef(1.0f - xp, xp));
        float ln = __logf(__fdividef(1.0f - xn, xn));
        float tp = 2.0f * xp - 1.0f, cp2 = 2.0f * xp * (1.0f - xp);
        float sum = Ap[0] * tp, pkm1 = 1.0f, pk = tp;
        #pragma unroll
        for (int k = 1; k < 13; ++k) {
            float pk1 = pk * tp;
            sum = __fmaf_rn(Ap[k], pk1, sum);
            sum = __fmaf_rn(-Apk[k] * cp2, pkm1, sum);
            pkm1 = pk; pk = pk1;
        }
        float tn = 2.0f * xn - 1.0f;
        op[t] = (U0P - U0N) + coefL * (lp - ln) + (sum - An0 * tn) * invF - Vo - Vsn - Vsp;
    }
}

extern "C" void kernel_launch(void* const* d_in, const int* in_sizes, int n_in,
                              void* d_out, int out_size, void* d_ws, size_t ws_size,
                              hipStream_t stream) {
    const float* current    = (const float*)d_in[0];
    const float* init_state = (const float*)d_in[1];
    const float* Ap_scale   = (const float*)d_in[2];
    const float* An0_scale  = (const float*)d_in[3];
    float* out = (float*)d_out;

    const int B = in_sizes[1] / 8;   // init_state is [B,8]
    const int T = in_sizes[0] / B;   // current is [B,T]

    if (T <= 1024) {
        // one 64-lane wave per batch element, 4 waves per 256-thread block
        dim3 block(256);
        dim3 grid((B + 3) / 4);
        hipLaunchKernelGGL(battery_scan_kernel, grid, block, 0, stream,
                           current, init_state, Ap_scale, An0_scale, out, B, T);
    } else {
        dim3 block(64);
        dim3 grid((B + 63) / 64);
        hipLaunchKernelGGL(battery_serial_kernel, grid, block, 0, stream,
                           current, init_state, Ap_scale, An0_scale, out, B, T);
    }
}